// Round 2
// baseline (2622.050 us; speedup 1.0000x reference)
//
#include <hip/hip_runtime.h>

// Problem constants
constexpr int Bn  = 128;
constexpr int Tn  = 48000;
constexpr int NFn = 2999;   // fast frames
constexpr int NSn = 999;    // slow frames
constexpr int G3n = 192;    // 3*GH
constexpr int GHn = 64;

typedef float f2 __attribute__((ext_vector_type(2)));

// ---------------------------------------------------------------------------
// Kernel 1: GI[b, t, j] = b_ih[j] + sum_{k<96} x[b, t*48+k] * W_ih[j, k]
// (unchanged from round 1)
// ---------------------------------------------------------------------------
__global__ __launch_bounds__(192) void gi_kernel(const float* __restrict__ x,
                                                 const float* __restrict__ W_ih,
                                                 const float* __restrict__ b_ih,
                                                 float* __restrict__ GI) {
  __shared__ __align__(16) float WT[48 * 196];   // [k][j] padded stride 196
  __shared__ float xs[1584];                     // 31*48+96 samples
  const int tile = blockIdx.x;        // 0..31
  const int b    = blockIdx.y;        // 0..127
  const int t0   = tile * 32;
  const int nt   = min(32, NSn - t0); // 32 or 7 (last tile)
  const int tid  = threadIdx.x;

  const int span = (nt - 1) * 48 + 96;
  for (int i = tid; i < 1584; i += 192)
    xs[i] = (i < span) ? x[(size_t)b * Tn + t0 * 48 + i] : 0.0f;

  const int jq = tid % 48;   // j-quad index
  const int tg = tid / 48;   // t-group (0..3)
  const int j0 = jq * 4;

  float acc[8][4];
#pragma unroll
  for (int u = 0; u < 8; ++u)
#pragma unroll
    for (int jj = 0; jj < 4; ++jj) acc[u][jj] = b_ih[j0 + jj];

  for (int half = 0; half < 2; ++half) {
    __syncthreads();
    for (int e = tid; e < 192 * 48; e += 192) {
      int j = e / 48, k = e % 48;
      WT[k * 196 + j] = W_ih[j * 96 + half * 48 + k];
    }
    __syncthreads();
    for (int k = 0; k < 48; ++k) {
      float4 w = *(const float4*)&WT[k * 196 + j0];
#pragma unroll
      for (int u = 0; u < 8; ++u) {
        float xv = xs[(tg * 8 + u) * 48 + half * 48 + k];
        acc[u][0] = fmaf(xv, w.x, acc[u][0]);
        acc[u][1] = fmaf(xv, w.y, acc[u][1]);
        acc[u][2] = fmaf(xv, w.z, acc[u][2]);
        acc[u][3] = fmaf(xv, w.w, acc[u][3]);
      }
    }
  }

#pragma unroll
  for (int u = 0; u < 8; ++u) {
    int tl = tg * 8 + u;
    if (tl < nt) {
      float4 st = make_float4(acc[u][0], acc[u][1], acc[u][2], acc[u][3]);
      *(float4*)&GI[(size_t)(b * NSn + t0 + tl) * G3n + j0] = st;
    }
  }
}

// ---------------------------------------------------------------------------
// Kernel 2: GRU, one WAVE (64 threads) per batch element. Thread j owns all
// three gate rows (r_j, z_j, n_j) in VGPRs, so the gating needs no
// cross-thread communication. Only sharing: h broadcast via 64-float LDS
// buffer. Block = 1 wave => wave-synchronous, barriers are free/elided.
// Dots use f2 vectors + 4 independent accumulators (v_pk_fma_f32, short
// dependency chains).
// ---------------------------------------------------------------------------
__device__ __forceinline__ float fsigmoid(float v) {
  return __fdividef(1.0f, 1.0f + __expf(-v));
}
__device__ __forceinline__ float ftanh_f(float v) {
  return 1.0f - __fdividef(2.0f, __expf(2.0f * v) + 1.0f);
}

__global__ __launch_bounds__(64, 1) void gru_kernel(const float* __restrict__ GI,
                                                    const float* __restrict__ W_hh,
                                                    const float* __restrict__ b_hh,
                                                    float* __restrict__ hs) {
  __shared__ __align__(16) float hbuf[64];
  const int b = blockIdx.x;
  const int j = threadIdx.x;

  f2 wr2[32], wz2[32], wn2[32];
  const f2* Wr = (const f2*)(W_hh + (size_t)j * 64);
  const f2* Wz = (const f2*)(W_hh + (size_t)(j + 64) * 64);
  const f2* Wn = (const f2*)(W_hh + (size_t)(j + 128) * 64);
#pragma unroll
  for (int q = 0; q < 32; ++q) { wr2[q] = Wr[q]; wz2[q] = Wz[q]; wn2[q] = Wn[q]; }
  const float br = b_hh[j], bz = b_hh[j + 64], bn = b_hh[j + 128];

  hbuf[j] = 0.0f;
  float hj = 0.0f;
  __syncthreads();

  const float* gp = GI + (size_t)b * NSn * G3n;
  float* hsp = hs + (size_t)b * NSn * GHn;

  float pr[3], pz[3], pn[3];
#pragma unroll
  for (int u = 0; u < 2; ++u) {
    pr[u] = gp[(size_t)u * G3n + j];
    pz[u] = gp[(size_t)u * G3n + 64 + j];
    pn[u] = gp[(size_t)u * G3n + 128 + j];
  }

  for (int t = 0; t < NSn; ++t) {
    // prefetch GI for t+2 (covers HBM latency; L3-resident after first pass)
    const size_t off = (size_t)min(t + 2, NSn - 1) * G3n;
    pr[2] = gp[off + j];
    pz[2] = gp[off + 64 + j];
    pn[2] = gp[off + 128 + j];

    const f2* h2 = (const f2*)hbuf;
    f2 ar0 = {0.f, 0.f}, ar1 = {0.f, 0.f}, ar2 = {0.f, 0.f}, ar3 = {0.f, 0.f};
    f2 az0 = {0.f, 0.f}, az1 = {0.f, 0.f}, az2 = {0.f, 0.f}, az3 = {0.f, 0.f};
    f2 an0 = {0.f, 0.f}, an1 = {0.f, 0.f}, an2 = {0.f, 0.f}, an3 = {0.f, 0.f};
#pragma unroll
    for (int q = 0; q < 8; ++q) {
      f2 h0 = h2[q * 4 + 0], h1 = h2[q * 4 + 1], h2v = h2[q * 4 + 2], h3 = h2[q * 4 + 3];
      ar0 += wr2[q * 4 + 0] * h0; ar1 += wr2[q * 4 + 1] * h1;
      ar2 += wr2[q * 4 + 2] * h2v; ar3 += wr2[q * 4 + 3] * h3;
      az0 += wz2[q * 4 + 0] * h0; az1 += wz2[q * 4 + 1] * h1;
      az2 += wz2[q * 4 + 2] * h2v; az3 += wz2[q * 4 + 3] * h3;
      an0 += wn2[q * 4 + 0] * h0; an1 += wn2[q * 4 + 1] * h1;
      an2 += wn2[q * 4 + 2] * h2v; an3 += wn2[q * 4 + 3] * h3;
    }
    f2 sr = (ar0 + ar1) + (ar2 + ar3);
    f2 sz = (az0 + az1) + (az2 + az3);
    f2 sn = (an0 + an1) + (an2 + an3);

    float r = fsigmoid(pr[0] + br + sr.x + sr.y);
    float z = fsigmoid(pz[0] + bz + sz.x + sz.y);
    float n = ftanh_f(fmaf(r, bn + sn.x + sn.y, pn[0]));
    float hn = fmaf(z, hj - n, n);          // (1-z)*n + z*h

    // All lanes' reads of hbuf are earlier DS ops of this same wave (in-order
    // DS pipe), so overwriting is safe; barrier (1 wave => ~free) publishes.
    hbuf[j] = hn;
    hj = hn;
    hsp[(size_t)t * GHn + j] = hn;
    __syncthreads();

    pr[0] = pr[1]; pr[1] = pr[2];
    pz[0] = pz[1]; pz[1] = pz[2];
    pn[0] = pn[1]; pn[1] = pn[2];
  }
}

// ---------------------------------------------------------------------------
// Kernel 3: fast path + overlap-add. Same tiling as round 1, but transposed
// weights padded to float4-friendly strides (68 / 36) and each thread
// computes 4 outputs via one float4 W read per k => 4x fewer LDS instrs.
// ---------------------------------------------------------------------------
__global__ __launch_bounds__(256) void out_kernel(const float* __restrict__ x,
                                                  const float* __restrict__ hs,
                                                  const float* __restrict__ W_cs,
                                                  const float* __restrict__ b_cs,
                                                  const float* __restrict__ W1,
                                                  const float* __restrict__ b1,
                                                  const float* __restrict__ W2,
                                                  const float* __restrict__ b2,
                                                  float* __restrict__ out) {
  __shared__ __align__(16) float xsl[544];
  __shared__ __align__(16) float W1T[64 * 68];   // [k][o] stride 68 (f4-aligned)
  __shared__ __align__(16) float W2T[64 * 36];   // [k][o] stride 36
  __shared__ __align__(16) float WcT[64 * 36];   // [k][i] stride 36
  __shared__ __align__(16) float cloc[33 * 32];
  __shared__ __align__(16) float h1loc[33 * 64];
  __shared__ __align__(16) float yloc[33 * 32];
  __shared__ __align__(16) float hrows[12 * 64];
  __shared__ __align__(16) float bb1[64];
  __shared__ __align__(16) float bb2[32];
  __shared__ __align__(16) float bcs[32];

  const int fb  = blockIdx.x;
  const int b   = blockIdx.y;
  const int f0  = fb * 32;
  const int nf  = min(33, NFn - f0);
  const int tid = threadIdx.x;

  for (int i = tid; i < 544; i += 256) {
    int g = f0 * 16 + i;
    xsl[i] = (g < Tn) ? x[(size_t)b * Tn + g] : 0.0f;
  }
  for (int e = tid; e < 64 * 64; e += 256) {
    int o = e >> 6, k = e & 63;
    W1T[k * 68 + o] = W1[e];
  }
  for (int e = tid; e < 32 * 64; e += 256) {
    int o = e >> 6, k = e & 63;
    W2T[k * 36 + o] = W2[e];
    WcT[k * 36 + o] = W_cs[e];
  }
  const int ts_base = max(f0 / 3 - 1, 0);
  const int ts_max  = max((f0 + nf - 1) / 3 - 1, 0);
  const int cnt     = ts_max - ts_base + 1;   // <= 12
  for (int i = tid; i < cnt * 64; i += 256) {
    int ts = ts_base + (i >> 6);
    hrows[i] = hs[((size_t)b * NSn + ts) * GHn + (i & 63)];
  }
  if (tid < 64) bb1[tid] = b1[tid];
  if (tid < 32) { bb2[tid] = b2[tid]; bcs[tid] = b_cs[tid]; }
  __syncthreads();

  const float4* Wc4 = (const float4*)WcT;
  const float4* W14 = (const float4*)W1T;
  const float4* W24 = (const float4*)W2T;

  // conditioning: 4 outputs per thread-item
  for (int it = tid; it < nf * 8; it += 256) {
    int lf = it >> 3, oq = it & 7;
    int ts = max((f0 + lf) / 3 - 1, 0);
    const float* hr = &hrows[(ts - ts_base) * 64];
    float4 acc = *(const float4*)&bcs[oq * 4];
#pragma unroll
    for (int k = 0; k < 64; ++k) {
      float hv = hr[k];
      float4 w = Wc4[k * 9 + oq];
      acc.x = fmaf(w.x, hv, acc.x);
      acc.y = fmaf(w.y, hv, acc.y);
      acc.z = fmaf(w.z, hv, acc.z);
      acc.w = fmaf(w.w, hv, acc.w);
    }
    *(float4*)&cloc[lf * 32 + oq * 4] = acc;
  }
  __syncthreads();

  // h1 = relu(W1 @ [fast; c] + b1): 4 outputs per thread-item
  for (int it = tid; it < nf * 16; it += 256) {
    int lf = it >> 4, oq = it & 15;
    const float* xf = &xsl[lf * 16];
    const float* cf = &cloc[lf * 32];
    float4 acc = *(const float4*)&bb1[oq * 4];
#pragma unroll
    for (int k = 0; k < 32; ++k) {
      float xv = xf[k];
      float4 w = W14[k * 17 + oq];
      acc.x = fmaf(w.x, xv, acc.x);
      acc.y = fmaf(w.y, xv, acc.y);
      acc.z = fmaf(w.z, xv, acc.z);
      acc.w = fmaf(w.w, xv, acc.w);
    }
#pragma unroll
    for (int k = 0; k < 32; ++k) {
      float cv = cf[k];
      float4 w = W14[(k + 32) * 17 + oq];
      acc.x = fmaf(w.x, cv, acc.x);
      acc.y = fmaf(w.y, cv, acc.y);
      acc.z = fmaf(w.z, cv, acc.z);
      acc.w = fmaf(w.w, cv, acc.w);
    }
    acc.x = fmaxf(acc.x, 0.0f); acc.y = fmaxf(acc.y, 0.0f);
    acc.z = fmaxf(acc.z, 0.0f); acc.w = fmaxf(acc.w, 0.0f);
    *(float4*)&h1loc[lf * 64 + oq * 4] = acc;
  }
  __syncthreads();

  // y = W2 @ h1 + b2: 4 outputs per thread-item
  for (int it = tid; it < nf * 8; it += 256) {
    int lf = it >> 3, oq = it & 7;
    const float* hf = &h1loc[lf * 64];
    float4 acc = *(const float4*)&bb2[oq * 4];
#pragma unroll
    for (int k = 0; k < 64; ++k) {
      float hv = hf[k];
      float4 w = W24[k * 9 + oq];
      acc.x = fmaf(w.x, hv, acc.x);
      acc.y = fmaf(w.y, hv, acc.y);
      acc.z = fmaf(w.z, hv, acc.z);
      acc.w = fmaf(w.w, hv, acc.w);
    }
    *(float4*)&yloc[lf * 32 + oq * 4] = acc;
  }
  __syncthreads();

  // overlap-add: sample s gets y[f1][s%16] (if f1 valid) + y[f1-1][s%16+16]
  const int s0 = f0 * 16 + 16;
  const int s1 = min(s0 + 512, Tn);
  for (int s = s0 + tid; s < s1; s += 256) {
    int f1  = s >> 4;
    int o1  = s & 15;
    int lf1 = f1 - f0;                       // in [1, 32]
    float v = yloc[(lf1 - 1) * 32 + o1 + 16];
    if (lf1 < nf) v += yloc[lf1 * 32 + o1];
    out[(size_t)b * Tn + s] = v;
  }
  if (fb == 0 && tid < 16) out[(size_t)b * Tn + tid] = yloc[tid];
}

// ---------------------------------------------------------------------------
extern "C" void kernel_launch(void* const* d_in, const int* in_sizes, int n_in,
                              void* d_out, int out_size, void* d_ws, size_t ws_size,
                              hipStream_t stream) {
  const float* x    = (const float*)d_in[0];
  const float* W_ih = (const float*)d_in[1];
  const float* W_hh = (const float*)d_in[2];
  const float* b_ih = (const float*)d_in[3];
  const float* b_hh = (const float*)d_in[4];
  const float* W_cs = (const float*)d_in[5];
  const float* b_cs = (const float*)d_in[6];
  const float* W1   = (const float*)d_in[7];
  const float* b1   = (const float*)d_in[8];
  const float* W2   = (const float*)d_in[9];
  const float* b2   = (const float*)d_in[10];
  float* out = (float*)d_out;

  float* GI = (float*)d_ws;                        // 128*999*192 fp32 = 98.2MB
  float* hs = GI + (size_t)Bn * NSn * G3n;         // 128*999*64  fp32 = 32.7MB

  gi_kernel<<<dim3(32, Bn), 192, 0, stream>>>(x, W_ih, b_ih, GI);
  gru_kernel<<<Bn, 64, 0, stream>>>(GI, W_hh, b_hh, hs);
  out_kernel<<<dim3(94, Bn), 256, 0, stream>>>(x, hs, W_cs, b_cs, W1, b1, W2, b2, out);
}

// Round 3
// 888.902 us; speedup vs baseline: 2.9498x; 2.9498x over previous
//
#include <hip/hip_runtime.h>

// Problem constants
constexpr int Bn  = 128;
constexpr int Tn  = 48000;
constexpr int NFn = 2999;   // fast frames
constexpr int NSn = 999;    // slow frames
constexpr int G3n = 192;    // 3*GH
constexpr int GHn = 64;

typedef float f2 __attribute__((ext_vector_type(2)));

// ---------------------------------------------------------------------------
// Kernel 1: GI[b, t, j] = b_ih[j] + sum_{k<96} x[b, t*48+k] * W_ih[j, k]
// (unchanged — known-good, no spills)
// ---------------------------------------------------------------------------
__global__ __launch_bounds__(192) void gi_kernel(const float* __restrict__ x,
                                                 const float* __restrict__ W_ih,
                                                 const float* __restrict__ b_ih,
                                                 float* __restrict__ GI) {
  __shared__ __align__(16) float WT[48 * 196];   // [k][j] padded stride 196
  __shared__ float xs[1584];                     // 31*48+96 samples
  const int tile = blockIdx.x;        // 0..31
  const int b    = blockIdx.y;        // 0..127
  const int t0   = tile * 32;
  const int nt   = min(32, NSn - t0); // 32 or 7 (last tile)
  const int tid  = threadIdx.x;

  const int span = (nt - 1) * 48 + 96;
  for (int i = tid; i < 1584; i += 192)
    xs[i] = (i < span) ? x[(size_t)b * Tn + t0 * 48 + i] : 0.0f;

  const int jq = tid % 48;   // j-quad index
  const int tg = tid / 48;   // t-group (0..3)
  const int j0 = jq * 4;

  float acc[8][4];
#pragma unroll
  for (int u = 0; u < 8; ++u)
#pragma unroll
    for (int jj = 0; jj < 4; ++jj) acc[u][jj] = b_ih[j0 + jj];

  for (int half = 0; half < 2; ++half) {
    __syncthreads();
    for (int e = tid; e < 192 * 48; e += 192) {
      int j = e / 48, k = e % 48;
      WT[k * 196 + j] = W_ih[j * 96 + half * 48 + k];
    }
    __syncthreads();
    for (int k = 0; k < 48; ++k) {
      float4 w = *(const float4*)&WT[k * 196 + j0];
#pragma unroll
      for (int u = 0; u < 8; ++u) {
        float xv = xs[(tg * 8 + u) * 48 + half * 48 + k];
        acc[u][0] = fmaf(xv, w.x, acc[u][0]);
        acc[u][1] = fmaf(xv, w.y, acc[u][1]);
        acc[u][2] = fmaf(xv, w.z, acc[u][2]);
        acc[u][3] = fmaf(xv, w.w, acc[u][3]);
      }
    }
  }

#pragma unroll
  for (int u = 0; u < 8; ++u) {
    int tl = tg * 8 + u;
    if (tl < nt) {
      float4 st = make_float4(acc[u][0], acc[u][1], acc[u][2], acc[u][3]);
      *(float4*)&GI[(size_t)(b * NSn + t0 + tl) * G3n + j0] = st;
    }
  }
}

// ---------------------------------------------------------------------------
// Kernel 2: GRU, one wave per batch element (unchanged from round 2 —
// it dropped out of the top-5).
// ---------------------------------------------------------------------------
__device__ __forceinline__ float fsigmoid(float v) {
  return __fdividef(1.0f, 1.0f + __expf(-v));
}
__device__ __forceinline__ float ftanh_f(float v) {
  return 1.0f - __fdividef(2.0f, __expf(2.0f * v) + 1.0f);
}

__global__ __launch_bounds__(64, 1) void gru_kernel(const float* __restrict__ GI,
                                                    const float* __restrict__ W_hh,
                                                    const float* __restrict__ b_hh,
                                                    float* __restrict__ hs) {
  __shared__ __align__(16) float hbuf[64];
  const int b = blockIdx.x;
  const int j = threadIdx.x;

  f2 wr2[32], wz2[32], wn2[32];
  const f2* Wr = (const f2*)(W_hh + (size_t)j * 64);
  const f2* Wz = (const f2*)(W_hh + (size_t)(j + 64) * 64);
  const f2* Wn = (const f2*)(W_hh + (size_t)(j + 128) * 64);
#pragma unroll
  for (int q = 0; q < 32; ++q) { wr2[q] = Wr[q]; wz2[q] = Wz[q]; wn2[q] = Wn[q]; }
  const float br = b_hh[j], bz = b_hh[j + 64], bn = b_hh[j + 128];

  hbuf[j] = 0.0f;
  float hj = 0.0f;
  __syncthreads();

  const float* gp = GI + (size_t)b * NSn * G3n;
  float* hsp = hs + (size_t)b * NSn * GHn;

  float pr[3], pz[3], pn[3];
#pragma unroll
  for (int u = 0; u < 2; ++u) {
    pr[u] = gp[(size_t)u * G3n + j];
    pz[u] = gp[(size_t)u * G3n + 64 + j];
    pn[u] = gp[(size_t)u * G3n + 128 + j];
  }

  for (int t = 0; t < NSn; ++t) {
    const size_t off = (size_t)min(t + 2, NSn - 1) * G3n;
    pr[2] = gp[off + j];
    pz[2] = gp[off + 64 + j];
    pn[2] = gp[off + 128 + j];

    const f2* h2 = (const f2*)hbuf;
    f2 ar0 = {0.f, 0.f}, ar1 = {0.f, 0.f}, ar2 = {0.f, 0.f}, ar3 = {0.f, 0.f};
    f2 az0 = {0.f, 0.f}, az1 = {0.f, 0.f}, az2 = {0.f, 0.f}, az3 = {0.f, 0.f};
    f2 an0 = {0.f, 0.f}, an1 = {0.f, 0.f}, an2 = {0.f, 0.f}, an3 = {0.f, 0.f};
#pragma unroll
    for (int q = 0; q < 8; ++q) {
      f2 h0 = h2[q * 4 + 0], h1 = h2[q * 4 + 1], h2v = h2[q * 4 + 2], h3 = h2[q * 4 + 3];
      ar0 += wr2[q * 4 + 0] * h0; ar1 += wr2[q * 4 + 1] * h1;
      ar2 += wr2[q * 4 + 2] * h2v; ar3 += wr2[q * 4 + 3] * h3;
      az0 += wz2[q * 4 + 0] * h0; az1 += wz2[q * 4 + 1] * h1;
      az2 += wz2[q * 4 + 2] * h2v; az3 += wz2[q * 4 + 3] * h3;
      an0 += wn2[q * 4 + 0] * h0; an1 += wn2[q * 4 + 1] * h1;
      an2 += wn2[q * 4 + 2] * h2v; an3 += wn2[q * 4 + 3] * h3;
    }
    f2 sr = (ar0 + ar1) + (ar2 + ar3);
    f2 sz = (az0 + az1) + (az2 + az3);
    f2 sn = (an0 + an1) + (an2 + an3);

    float r = fsigmoid(pr[0] + br + sr.x + sr.y);
    float z = fsigmoid(pz[0] + bz + sz.x + sz.y);
    float n = ftanh_f(fmaf(r, bn + sn.x + sn.y, pn[0]));
    float hn = fmaf(z, hj - n, n);          // (1-z)*n + z*h

    hbuf[j] = hn;
    hj = hn;
    hsp[(size_t)t * GHn + j] = hn;
    __syncthreads();

    pr[0] = pr[1]; pr[1] = pr[2];
    pz[0] = pz[1]; pz[1] = pz[2];
    pn[0] = pn[1]; pn[1] = pn[2];
  }
}

// ---------------------------------------------------------------------------
// Kernel 2b: cs[b, ts, i] = b_cs[i] + sum_k hs[b, ts, k] * W_cs[i, k]
// One block = one b, 32 ts values. Thread = (ts-local, output-quad).
// ---------------------------------------------------------------------------
__global__ __launch_bounds__(256) void cs_kernel(const float* __restrict__ hs,
                                                 const float* __restrict__ W_cs,
                                                 const float* __restrict__ b_cs,
                                                 float* __restrict__ cs) {
  __shared__ __align__(16) float WcT[64 * 36];  // [k][i] stride 36
  __shared__ __align__(16) float hsl[32 * 65];  // [t][k] stride 65
  __shared__ __align__(16) float bcs[32];
  const int tile = blockIdx.x;   // 0..31
  const int b    = blockIdx.y;
  const int t0   = tile * 32;
  const int nt   = min(32, NSn - t0);
  const int tid  = threadIdx.x;

  for (int e = tid; e < 32 * 64; e += 256) {
    int i = e >> 6, k = e & 63;
    WcT[k * 36 + i] = W_cs[e];
  }
  for (int e = tid; e < nt * 64; e += 256) {
    int t = e >> 6, k = e & 63;
    hsl[t * 65 + k] = hs[((size_t)b * NSn + t0 + t) * GHn + k];
  }
  if (tid < 32) bcs[tid] = b_cs[tid];
  __syncthreads();

  const int oq = tid & 7;    // output quad 0..7
  const int t  = tid >> 3;   // 0..31
  if (t < nt) {
    float4 acc = *(const float4*)&bcs[oq * 4];
    const float* hr = &hsl[t * 65];
#pragma unroll 4
    for (int k = 0; k < 64; ++k) {
      float hv = hr[k];
      float4 w = *(const float4*)&WcT[k * 36 + oq * 4];
      acc.x = fmaf(w.x, hv, acc.x);
      acc.y = fmaf(w.y, hv, acc.y);
      acc.z = fmaf(w.z, hv, acc.z);
      acc.w = fmaf(w.w, hv, acc.w);
    }
    *(float4*)&cs[((size_t)b * NSn + t0 + t) * 32 + oq * 4] = acc;
  }
}

// ---------------------------------------------------------------------------
// Kernel 3: fast MLP + overlap-add. Activations A[lf][64] = [x-frame | c]
// staged at stride 65 (conflict-free across lf); weights transposed at
// f4-aligned strides; 4 outputs/thread, k-loop capped at unroll 4 so the
// allocator never sees >~16 live LDS results (round-2 spill fix).
// ---------------------------------------------------------------------------
__global__ __launch_bounds__(256) void out_kernel(const float* __restrict__ x,
                                                  const float* __restrict__ cs,
                                                  const float* __restrict__ W1,
                                                  const float* __restrict__ b1,
                                                  const float* __restrict__ W2,
                                                  const float* __restrict__ b2,
                                                  float* __restrict__ out) {
  __shared__ __align__(16) float A[33 * 65];     // [lf][k], k<32 = x, k>=32 = c
  __shared__ __align__(16) float W1T[64 * 68];   // [k][o] stride 68
  __shared__ __align__(16) float W2T[64 * 36];   // [k][o] stride 36
  __shared__ __align__(16) float h1loc[33 * 65]; // [lf][o] stride 65
  __shared__ __align__(16) float yloc[33 * 32];
  __shared__ __align__(16) float bb1[64];
  __shared__ __align__(16) float bb2[32];

  const int fb  = blockIdx.x;
  const int b   = blockIdx.y;
  const int f0  = fb * 32;
  const int nf  = min(33, NFn - f0);
  const int tid = threadIdx.x;

  for (int e = tid; e < 64 * 64; e += 256) {
    int o = e >> 6, k = e & 63;
    W1T[k * 68 + o] = W1[e];
  }
  for (int e = tid; e < 32 * 64; e += 256) {
    int o = e >> 6, k = e & 63;
    W2T[k * 36 + o] = W2[e];
  }
  if (tid < 64) bb1[tid] = b1[tid];
  if (tid < 32) bb2[tid] = b2[tid];

  for (int e = tid; e < 33 * 32; e += 256) {
    int lf = e >> 5, k = e & 31;
    int g = (f0 + lf) * 16 + k;
    A[lf * 65 + k] = (lf < nf && g < Tn) ? x[(size_t)b * Tn + g] : 0.0f;
  }
  for (int e = tid; e < 33 * 32; e += 256) {
    int lf = e >> 5, k = e & 31;
    int ts = max((f0 + lf) / 3 - 1, 0);
    A[lf * 65 + 32 + k] = (lf < nf) ? cs[((size_t)b * NSn + ts) * 32 + k] : 0.0f;
  }
  __syncthreads();

  // h1 = relu(W1 @ A + b1): item = (lf, oq), 4 outputs each
  for (int it = tid; it < 33 * 16; it += 256) {
    int lf = it >> 4, oq = it & 15;
    float4 acc = *(const float4*)&bb1[oq * 4];
    const float* ar = &A[lf * 65];
#pragma unroll 4
    for (int k = 0; k < 64; ++k) {
      float av = ar[k];
      float4 w = *(const float4*)&W1T[k * 68 + oq * 4];
      acc.x = fmaf(w.x, av, acc.x);
      acc.y = fmaf(w.y, av, acc.y);
      acc.z = fmaf(w.z, av, acc.z);
      acc.w = fmaf(w.w, av, acc.w);
    }
    acc.x = fmaxf(acc.x, 0.0f); acc.y = fmaxf(acc.y, 0.0f);
    acc.z = fmaxf(acc.z, 0.0f); acc.w = fmaxf(acc.w, 0.0f);
    *(float4*)&h1loc[lf * 65 + oq * 4] = acc;
  }
  __syncthreads();

  // y = W2 @ h1 + b2: item = (lf, oq), 4 outputs each
  for (int it = tid; it < 33 * 8; it += 256) {
    int lf = it >> 3, oq = it & 7;
    float4 acc = *(const float4*)&bb2[oq * 4];
    const float* hr = &h1loc[lf * 65];
#pragma unroll 4
    for (int k = 0; k < 64; ++k) {
      float hv = hr[k];
      float4 w = *(const float4*)&W2T[k * 36 + oq * 4];
      acc.x = fmaf(w.x, hv, acc.x);
      acc.y = fmaf(w.y, hv, acc.y);
      acc.z = fmaf(w.z, hv, acc.z);
      acc.w = fmaf(w.w, hv, acc.w);
    }
    *(float4*)&yloc[lf * 32 + oq * 4] = acc;
  }
  __syncthreads();

  // overlap-add: sample s gets y[f1][s%16] (if f1 valid) + y[f1-1][s%16+16]
  const int s0 = f0 * 16 + 16;
  const int s1 = min(s0 + 512, Tn);
  for (int s = s0 + tid; s < s1; s += 256) {
    int f1  = s >> 4;
    int o1  = s & 15;
    int lf1 = f1 - f0;                       // in [1, 32]
    float v = yloc[(lf1 - 1) * 32 + o1 + 16];
    if (lf1 < nf) v += yloc[lf1 * 32 + o1];
    out[(size_t)b * Tn + s] = v;
  }
  if (fb == 0 && tid < 16) out[(size_t)b * Tn + tid] = yloc[tid];
}

// ---------------------------------------------------------------------------
extern "C" void kernel_launch(void* const* d_in, const int* in_sizes, int n_in,
                              void* d_out, int out_size, void* d_ws, size_t ws_size,
                              hipStream_t stream) {
  const float* x    = (const float*)d_in[0];
  const float* W_ih = (const float*)d_in[1];
  const float* W_hh = (const float*)d_in[2];
  const float* b_ih = (const float*)d_in[3];
  const float* b_hh = (const float*)d_in[4];
  const float* W_cs = (const float*)d_in[5];
  const float* b_cs = (const float*)d_in[6];
  const float* W1   = (const float*)d_in[7];
  const float* b1   = (const float*)d_in[8];
  const float* W2   = (const float*)d_in[9];
  const float* b2   = (const float*)d_in[10];
  float* out = (float*)d_out;

  float* GI = (float*)d_ws;                        // 128*999*192 fp32 = 98.2MB
  float* hs = GI + (size_t)Bn * NSn * G3n;         // 128*999*64  fp32 = 32.7MB
  float* cs = GI;                                  // reuse GI (dead after gru)

  gi_kernel<<<dim3(32, Bn), 192, 0, stream>>>(x, W_ih, b_ih, GI);
  gru_kernel<<<Bn, 64, 0, stream>>>(GI, W_hh, b_hh, hs);
  cs_kernel<<<dim3(32, Bn), 256, 0, stream>>>(hs, W_cs, b_cs, cs);
  out_kernel<<<dim3(94, Bn), 256, 0, stream>>>(x, cs, W1, b1, W2, b2, out);
}

// Round 4
// 880.089 us; speedup vs baseline: 2.9793x; 1.0100x over previous
//
#include <hip/hip_runtime.h>

// Problem constants
constexpr int Bn  = 128;
constexpr int Tn  = 48000;
constexpr int NFn = 2999;   // fast frames
constexpr int NSn = 999;    // slow frames
constexpr int G3n = 192;    // 3*GH
constexpr int GHn = 64;

typedef float f2 __attribute__((ext_vector_type(2)));

// ---------------------------------------------------------------------------
// Kernel 1: GI[b, t, j] = b_ih[j] + sum_{k<96} x[b, t*48+k] * W_ih[j, k]
// (unchanged — known-good, no spills)
// ---------------------------------------------------------------------------
__global__ __launch_bounds__(192) void gi_kernel(const float* __restrict__ x,
                                                 const float* __restrict__ W_ih,
                                                 const float* __restrict__ b_ih,
                                                 float* __restrict__ GI) {
  __shared__ __align__(16) float WT[48 * 196];   // [k][j] padded stride 196
  __shared__ float xs[1584];                     // 31*48+96 samples
  const int tile = blockIdx.x;        // 0..31
  const int b    = blockIdx.y;        // 0..127
  const int t0   = tile * 32;
  const int nt   = min(32, NSn - t0); // 32 or 7 (last tile)
  const int tid  = threadIdx.x;

  const int span = (nt - 1) * 48 + 96;
  for (int i = tid; i < 1584; i += 192)
    xs[i] = (i < span) ? x[(size_t)b * Tn + t0 * 48 + i] : 0.0f;

  const int jq = tid % 48;   // j-quad index
  const int tg = tid / 48;   // t-group (0..3)
  const int j0 = jq * 4;

  float acc[8][4];
#pragma unroll
  for (int u = 0; u < 8; ++u)
#pragma unroll
    for (int jj = 0; jj < 4; ++jj) acc[u][jj] = b_ih[j0 + jj];

  for (int half = 0; half < 2; ++half) {
    __syncthreads();
    for (int e = tid; e < 192 * 48; e += 192) {
      int j = e / 48, k = e % 48;
      WT[k * 196 + j] = W_ih[j * 96 + half * 48 + k];
    }
    __syncthreads();
    for (int k = 0; k < 48; ++k) {
      float4 w = *(const float4*)&WT[k * 196 + j0];
#pragma unroll
      for (int u = 0; u < 8; ++u) {
        float xv = xs[(tg * 8 + u) * 48 + half * 48 + k];
        acc[u][0] = fmaf(xv, w.x, acc[u][0]);
        acc[u][1] = fmaf(xv, w.y, acc[u][1]);
        acc[u][2] = fmaf(xv, w.z, acc[u][2]);
        acc[u][3] = fmaf(xv, w.w, acc[u][3]);
      }
    }
  }

#pragma unroll
  for (int u = 0; u < 8; ++u) {
    int tl = tg * 8 + u;
    if (tl < nt) {
      float4 st = make_float4(acc[u][0], acc[u][1], acc[u][2], acc[u][3]);
      *(float4*)&GI[(size_t)(b * NSn + t0 + tl) * G3n + j0] = st;
    }
  }
}

// ---------------------------------------------------------------------------
// Kernel 2: GRU, one wave per batch element. Thread j owns gate rows
// (r_j, z_j, n_j) in VGPRs; h broadcast via 64-float LDS buffer.
// NO __syncthreads in the step loop: single wave => LDS DS pipe is in-order,
// so the ds_write of h_t is observed by the following ds_reads. We only need
// __builtin_amdgcn_wave_barrier() (zero-cost compiler fence) to pin ordering.
// This keeps GI prefetch loads in flight across steps (no vmcnt(0) drain —
// the round-3 stall).
// ---------------------------------------------------------------------------
__device__ __forceinline__ float fsigmoid(float v) {
  return __fdividef(1.0f, 1.0f + __expf(-v));
}
__device__ __forceinline__ float ftanh_f(float v) {
  return 1.0f - __fdividef(2.0f, __expf(2.0f * v) + 1.0f);
}

__global__ __launch_bounds__(64, 1) void gru_kernel(const float* __restrict__ GI,
                                                    const float* __restrict__ W_hh,
                                                    const float* __restrict__ b_hh,
                                                    float* __restrict__ hs) {
  __shared__ __align__(16) float hbuf[64];
  const int b = blockIdx.x;
  const int j = threadIdx.x;

  f2 wr2[32], wz2[32], wn2[32];
  const f2* Wr = (const f2*)(W_hh + (size_t)j * 64);
  const f2* Wz = (const f2*)(W_hh + (size_t)(j + 64) * 64);
  const f2* Wn = (const f2*)(W_hh + (size_t)(j + 128) * 64);
#pragma unroll
  for (int q = 0; q < 32; ++q) { wr2[q] = Wr[q]; wz2[q] = Wz[q]; wn2[q] = Wn[q]; }
  const float br = b_hh[j], bz = b_hh[j + 64], bn = b_hh[j + 128];

  hbuf[j] = 0.0f;
  float hj = 0.0f;
  __builtin_amdgcn_wave_barrier();

  const float* gp = GI + (size_t)b * NSn * G3n;
  float* hsp = hs + (size_t)b * NSn * GHn;

  float pr[3], pz[3], pn[3];
#pragma unroll
  for (int u = 0; u < 2; ++u) {
    pr[u] = gp[(size_t)u * G3n + j];
    pz[u] = gp[(size_t)u * G3n + 64 + j];
    pn[u] = gp[(size_t)u * G3n + 128 + j];
  }

  for (int t = 0; t < NSn; ++t) {
    const size_t off = (size_t)min(t + 2, NSn - 1) * G3n;
    pr[2] = gp[off + j];
    pz[2] = gp[off + 64 + j];
    pn[2] = gp[off + 128 + j];

    const f2* h2 = (const f2*)hbuf;
    f2 ar0 = {0.f, 0.f}, ar1 = {0.f, 0.f}, ar2 = {0.f, 0.f}, ar3 = {0.f, 0.f};
    f2 az0 = {0.f, 0.f}, az1 = {0.f, 0.f}, az2 = {0.f, 0.f}, az3 = {0.f, 0.f};
    f2 an0 = {0.f, 0.f}, an1 = {0.f, 0.f}, an2 = {0.f, 0.f}, an3 = {0.f, 0.f};
#pragma unroll
    for (int q = 0; q < 8; ++q) {
      f2 h0 = h2[q * 4 + 0], h1 = h2[q * 4 + 1], h2v = h2[q * 4 + 2], h3 = h2[q * 4 + 3];
      ar0 += wr2[q * 4 + 0] * h0; ar1 += wr2[q * 4 + 1] * h1;
      ar2 += wr2[q * 4 + 2] * h2v; ar3 += wr2[q * 4 + 3] * h3;
      az0 += wz2[q * 4 + 0] * h0; az1 += wz2[q * 4 + 1] * h1;
      az2 += wz2[q * 4 + 2] * h2v; az3 += wz2[q * 4 + 3] * h3;
      an0 += wn2[q * 4 + 0] * h0; an1 += wn2[q * 4 + 1] * h1;
      an2 += wn2[q * 4 + 2] * h2v; an3 += wn2[q * 4 + 3] * h3;
    }
    f2 sr = (ar0 + ar1) + (ar2 + ar3);
    f2 sz = (az0 + az1) + (az2 + az3);
    f2 sn = (an0 + an1) + (an2 + an3);

    float r = fsigmoid(pr[0] + br + sr.x + sr.y);
    float z = fsigmoid(pz[0] + bz + sz.x + sz.y);
    float n = ftanh_f(fmaf(r, bn + sn.x + sn.y, pn[0]));
    float hn = fmaf(z, hj - n, n);          // (1-z)*n + z*h

    // Pin ordering: all reads of hbuf (above) stay before the write; the
    // write stays before next iteration's reads. DS pipe in-order per wave
    // guarantees read-after-write data correctness without s_barrier.
    __builtin_amdgcn_wave_barrier();
    hbuf[j] = hn;
    __builtin_amdgcn_wave_barrier();
    hj = hn;
    hsp[(size_t)t * GHn + j] = hn;

    pr[0] = pr[1]; pr[1] = pr[2];
    pz[0] = pz[1]; pz[1] = pz[2];
    pn[0] = pn[1]; pn[1] = pn[2];
  }
}

// ---------------------------------------------------------------------------
// Kernel 2b: cs[b, ts, i] = b_cs[i] + sum_k hs[b, ts, k] * W_cs[i, k]
// (unchanged)
// ---------------------------------------------------------------------------
__global__ __launch_bounds__(256) void cs_kernel(const float* __restrict__ hs,
                                                 const float* __restrict__ W_cs,
                                                 const float* __restrict__ b_cs,
                                                 float* __restrict__ cs) {
  __shared__ __align__(16) float WcT[64 * 36];  // [k][i] stride 36
  __shared__ __align__(16) float hsl[32 * 65];  // [t][k] stride 65
  __shared__ __align__(16) float bcs[32];
  const int tile = blockIdx.x;   // 0..31
  const int b    = blockIdx.y;
  const int t0   = tile * 32;
  const int nt   = min(32, NSn - t0);
  const int tid  = threadIdx.x;

  for (int e = tid; e < 32 * 64; e += 256) {
    int i = e >> 6, k = e & 63;
    WcT[k * 36 + i] = W_cs[e];
  }
  for (int e = tid; e < nt * 64; e += 256) {
    int t = e >> 6, k = e & 63;
    hsl[t * 65 + k] = hs[((size_t)b * NSn + t0 + t) * GHn + k];
  }
  if (tid < 32) bcs[tid] = b_cs[tid];
  __syncthreads();

  const int oq = tid & 7;    // output quad 0..7
  const int t  = tid >> 3;   // 0..31
  if (t < nt) {
    float4 acc = *(const float4*)&bcs[oq * 4];
    const float* hr = &hsl[t * 65];
#pragma unroll 4
    for (int k = 0; k < 64; ++k) {
      float hv = hr[k];
      float4 w = *(const float4*)&WcT[k * 36 + oq * 4];
      acc.x = fmaf(w.x, hv, acc.x);
      acc.y = fmaf(w.y, hv, acc.y);
      acc.z = fmaf(w.z, hv, acc.z);
      acc.w = fmaf(w.w, hv, acc.w);
    }
    *(float4*)&cs[((size_t)b * NSn + t0 + t) * 32 + oq * 4] = acc;
  }
}

// ---------------------------------------------------------------------------
// Kernel 3: fast MLP + overlap-add (unchanged from round 3 — fixed)
// ---------------------------------------------------------------------------
__global__ __launch_bounds__(256) void out_kernel(const float* __restrict__ x,
                                                  const float* __restrict__ cs,
                                                  const float* __restrict__ W1,
                                                  const float* __restrict__ b1,
                                                  const float* __restrict__ W2,
                                                  const float* __restrict__ b2,
                                                  float* __restrict__ out) {
  __shared__ __align__(16) float A[33 * 65];     // [lf][k], k<32 = x, k>=32 = c
  __shared__ __align__(16) float W1T[64 * 68];   // [k][o] stride 68
  __shared__ __align__(16) float W2T[64 * 36];   // [k][o] stride 36
  __shared__ __align__(16) float h1loc[33 * 65]; // [lf][o] stride 65
  __shared__ __align__(16) float yloc[33 * 32];
  __shared__ __align__(16) float bb1[64];
  __shared__ __align__(16) float bb2[32];

  const int fb  = blockIdx.x;
  const int b   = blockIdx.y;
  const int f0  = fb * 32;
  const int nf  = min(33, NFn - f0);
  const int tid = threadIdx.x;

  for (int e = tid; e < 64 * 64; e += 256) {
    int o = e >> 6, k = e & 63;
    W1T[k * 68 + o] = W1[e];
  }
  for (int e = tid; e < 32 * 64; e += 256) {
    int o = e >> 6, k = e & 63;
    W2T[k * 36 + o] = W2[e];
  }
  if (tid < 64) bb1[tid] = b1[tid];
  if (tid < 32) bb2[tid] = b2[tid];

  for (int e = tid; e < 33 * 32; e += 256) {
    int lf = e >> 5, k = e & 31;
    int g = (f0 + lf) * 16 + k;
    A[lf * 65 + k] = (lf < nf && g < Tn) ? x[(size_t)b * Tn + g] : 0.0f;
  }
  for (int e = tid; e < 33 * 32; e += 256) {
    int lf = e >> 5, k = e & 31;
    int ts = max((f0 + lf) / 3 - 1, 0);
    A[lf * 65 + 32 + k] = (lf < nf) ? cs[((size_t)b * NSn + ts) * 32 + k] : 0.0f;
  }
  __syncthreads();

  // h1 = relu(W1 @ A + b1): item = (lf, oq), 4 outputs each
  for (int it = tid; it < 33 * 16; it += 256) {
    int lf = it >> 4, oq = it & 15;
    float4 acc = *(const float4*)&bb1[oq * 4];
    const float* ar = &A[lf * 65];
#pragma unroll 4
    for (int k = 0; k < 64; ++k) {
      float av = ar[k];
      float4 w = *(const float4*)&W1T[k * 68 + oq * 4];
      acc.x = fmaf(w.x, av, acc.x);
      acc.y = fmaf(w.y, av, acc.y);
      acc.z = fmaf(w.z, av, acc.z);
      acc.w = fmaf(w.w, av, acc.w);
    }
    acc.x = fmaxf(acc.x, 0.0f); acc.y = fmaxf(acc.y, 0.0f);
    acc.z = fmaxf(acc.z, 0.0f); acc.w = fmaxf(acc.w, 0.0f);
    *(float4*)&h1loc[lf * 65 + oq * 4] = acc;
  }
  __syncthreads();

  // y = W2 @ h1 + b2: item = (lf, oq), 4 outputs each
  for (int it = tid; it < 33 * 8; it += 256) {
    int lf = it >> 3, oq = it & 7;
    float4 acc = *(const float4*)&bb2[oq * 4];
    const float* hr = &h1loc[lf * 65];
#pragma unroll 4
    for (int k = 0; k < 64; ++k) {
      float hv = hr[k];
      float4 w = *(const float4*)&W2T[k * 36 + oq * 4];
      acc.x = fmaf(w.x, hv, acc.x);
      acc.y = fmaf(w.y, hv, acc.y);
      acc.z = fmaf(w.z, hv, acc.z);
      acc.w = fmaf(w.w, hv, acc.w);
    }
    *(float4*)&yloc[lf * 32 + oq * 4] = acc;
  }
  __syncthreads();

  // overlap-add: sample s gets y[f1][s%16] (if f1 valid) + y[f1-1][s%16+16]
  const int s0 = f0 * 16 + 16;
  const int s1 = min(s0 + 512, Tn);
  for (int s = s0 + tid; s < s1; s += 256) {
    int f1  = s >> 4;
    int o1  = s & 15;
    int lf1 = f1 - f0;                       // in [1, 32]
    float v = yloc[(lf1 - 1) * 32 + o1 + 16];
    if (lf1 < nf) v += yloc[lf1 * 32 + o1];
    out[(size_t)b * Tn + s] = v;
  }
  if (fb == 0 && tid < 16) out[(size_t)b * Tn + tid] = yloc[tid];
}

// ---------------------------------------------------------------------------
extern "C" void kernel_launch(void* const* d_in, const int* in_sizes, int n_in,
                              void* d_out, int out_size, void* d_ws, size_t ws_size,
                              hipStream_t stream) {
  const float* x    = (const float*)d_in[0];
  const float* W_ih = (const float*)d_in[1];
  const float* W_hh = (const float*)d_in[2];
  const float* b_ih = (const float*)d_in[3];
  const float* b_hh = (const float*)d_in[4];
  const float* W_cs = (const float*)d_in[5];
  const float* b_cs = (const float*)d_in[6];
  const float* W1   = (const float*)d_in[7];
  const float* b1   = (const float*)d_in[8];
  const float* W2   = (const float*)d_in[9];
  const float* b2   = (const float*)d_in[10];
  float* out = (float*)d_out;

  float* GI = (float*)d_ws;                        // 128*999*192 fp32 = 98.2MB
  float* hs = GI + (size_t)Bn * NSn * G3n;         // 128*999*64  fp32 = 32.7MB
  float* cs = GI;                                  // reuse GI (dead after gru)

  gi_kernel<<<dim3(32, Bn), 192, 0, stream>>>(x, W_ih, b_ih, GI);
  gru_kernel<<<Bn, 64, 0, stream>>>(GI, W_hh, b_hh, hs);
  cs_kernel<<<dim3(32, Bn), 256, 0, stream>>>(hs, W_cs, b_cs, cs);
  out_kernel<<<dim3(94, Bn), 256, 0, stream>>>(x, cs, W1, b1, W2, b2, out);
}